// Round 6
// baseline (121.243 us; speedup 1.0000x reference)
//
#include <hip/hip_runtime.h>

typedef __attribute__((ext_vector_type(8))) short short8;
typedef __attribute__((ext_vector_type(4))) float f32x4;

#define APITCH 264   // A-row pitch in shorts: 256 data + 8 pad (528B -> stride 4 banks, balanced)

// workspace layout (bytes)
#define WS_HID   0u        // 256*256 f32      = 262144
#define WS_P     262144u   // 131072 f32       = 524288  (ends 786432)
#define WS_Z     786432u   // 2048 f32         = 8192
#define WS_CTX   794624u   // 256*256 f32      = 262144
#define WS_CTXP  1056768u  // 8*256*256 f32    = 2097152 (ends 3153920)
#define WS_WBF   3153920u  // 256*256 bf16     = 131072  (ends 3284992)

__device__ __forceinline__ unsigned cvtpk(float lo, float hi) {
    unsigned r;
    asm("v_cvt_pk_bf16_f32 %0, %1, %2" : "=v"(r) : "v"(lo), "v"(hi));
    return r;   // low short = bf16(lo), high short = bf16(hi)
}
__device__ __forceinline__ int4 pack8(float4 x0, float4 x1) {
    int4 q;
    q.x = (int)cvtpk(x0.x, x0.y);
    q.y = (int)cvtpk(x0.z, x0.w);
    q.z = (int)cvtpk(x1.x, x1.y);
    q.w = (int)cvtpk(x1.z, x1.w);
    return q;
}
__device__ __forceinline__ float bf2f(unsigned s) {
    union { float f; unsigned u; } v; v.u = s << 16;
    return v.f;
}
__device__ __forceinline__ float tanh_fast(float x) {
    float e2 = __expf(2.f * x);
    return 1.f - 2.f * __builtin_amdgcn_rcpf(e2 + 1.f);
}
__device__ __forceinline__ float sigmoid_fast(float x) {
    return __builtin_amdgcn_rcpf(1.f + __expf(-x));
}

// ---------------- K0: hid GEMV + W_i2h -> bf16 (plain [256][256]) ----------------
__global__ __launch_bounds__(256) void k_prep(
    const float* __restrict__ prev_h, const float* __restrict__ W_i2h,
    const float* __restrict__ W_h2h, const float* __restrict__ b_h2h,
    float* __restrict__ hid, short* __restrict__ Wbf)
{
    int bid = blockIdx.x, tid = threadIdx.x;
    if (bid < 256) {                       // hid[b][h] = prev_h[b]·W_h2h[h] + b_h2h[h]
        __shared__ float ph[256];
        ph[tid] = prev_h[bid * 256 + tid];
        __syncthreads();
        float acc = b_h2h[tid];
        const float4* w = (const float4*)(W_h2h + tid * 256);
        #pragma unroll 8
        for (int k4 = 0; k4 < 64; ++k4) {
            float4 ww = w[k4];
            acc += ww.x * ph[k4*4+0] + ww.y * ph[k4*4+1] + ww.z * ph[k4*4+2] + ww.w * ph[k4*4+3];
        }
        hid[bid * 256 + tid] = acc;
    } else {                               // bf16 convert, 8 elems/thread
        int idx = ((bid - 256) * 256 + tid) * 8;   // < 65536
        float4 x0 = *(const float4*)(W_i2h + idx);
        float4 x1 = *(const float4*)(W_i2h + idx + 4);
        *(int4*)&Wbf[idx] = pack8(x0, x1);
    }
}

// ---------------- K1: fused e-score + exp + context partial (barrier-free K-loop) ----------------
// 2048 blocks x 256 threads (4 waves). Block = 64 bt-rows x 256 h-cols; wave w = col-panel w*64.
// A staged ONCE to LDS (1 barrier); B-frags direct 16B global loads from L2-resident Wbf.
// K-loop has no __syncthreads -> compiler pipelines freely, 3 blocks/CU overlap.
__global__ __launch_bounds__(256, 3) void k_escore_ctx(
    const float* __restrict__ BH, const short* __restrict__ Wbf,
    const float* __restrict__ hid, const float* __restrict__ Wsc,
    float* __restrict__ p_out, float* __restrict__ zbuf, float* __restrict__ ctxp)
{
    __shared__ short Al[64 * APITCH];           // 33792 B, A tile bf16
    __shared__ float eps[4 * 64];
    __shared__ float pl[64];
    __shared__ float r2[2 * 256];

    const int tid = threadIdx.x;
    const int lane = tid & 63;
    const int w = tid >> 6;                     // col-panel 0..3
    const int l15 = lane & 15, lg = lane >> 4;
    const int bt0 = blockIdx.x * 64;
    const int b = bt0 >> 9;
    const int c = (bt0 >> 6) & 7;

    // ---- stage A once: thread (arow, kq) converts 64 contiguous floats ----
    {
        const int arow = tid >> 2, kq = tid & 3;
        const float* as = BH + (size_t)(bt0 + arow) * 256 + kq * 64;
        short* dst = &Al[arow * APITCH + kq * 64];
        #pragma unroll
        for (int i = 0; i < 8; ++i) {
            float4 x0 = *(const float4*)(as + i * 8);
            float4 x1 = *(const float4*)(as + i * 8 + 4);
            *(int4*)(dst + i * 8) = pack8(x0, x1);
        }
    }
    __syncthreads();

    // ---- K-loop: zero barriers ----
    f32x4 acc[4][4];
    #pragma unroll
    for (int i = 0; i < 4; i++)
        #pragma unroll
        for (int j = 0; j < 4; j++) acc[i][j] = (f32x4){0.f, 0.f, 0.f, 0.f};

    const short* bbase = Wbf + (size_t)(w * 64) * 256 + lg * 8;
    #pragma unroll
    for (int ks = 0; ks < 8; ++ks) {
        short8 af[4], bfr[4];
        #pragma unroll
        for (int rf = 0; rf < 4; rf++)
            af[rf] = *(const short8*)&Al[(rf * 16 + l15) * APITCH + ks * 32 + lg * 8];
        #pragma unroll
        for (int cf = 0; cf < 4; cf++)
            bfr[cf] = *(const short8*)(bbase + (size_t)(cf * 16 + l15) * 256 + ks * 32);
        #pragma unroll
        for (int rf = 0; rf < 4; rf++)
            #pragma unroll
            for (int cf = 0; cf < 4; cf++)
                acc[rf][cf] = __builtin_amdgcn_mfma_f32_16x16x32_bf16(af[rf], bfr[cf], acc[rf][cf], 0, 0, 0);
    }

    // ---- e partials over this wave's 64 cols ----
    float esum[4][4];
    #pragma unroll
    for (int rf = 0; rf < 4; rf++)
        #pragma unroll
        for (int r = 0; r < 4; r++) esum[rf][r] = 0.f;

    #pragma unroll
    for (int cf = 0; cf < 4; cf++) {
        int col = w * 64 + cf * 16 + l15;
        float wsv = Wsc[col];
        float hd = hid[b * 256 + col];
        #pragma unroll
        for (int rf = 0; rf < 4; rf++)
            #pragma unroll
            for (int r = 0; r < 4; r++)
                esum[rf][r] += wsv * tanh_fast(acc[rf][cf][r] + hd);
    }
    #pragma unroll
    for (int rf = 0; rf < 4; rf++)
        #pragma unroll
        for (int r = 0; r < 4; r++) {
            float s = esum[rf][r];
            s += __shfl_xor(s, 1); s += __shfl_xor(s, 2);
            s += __shfl_xor(s, 4); s += __shfl_xor(s, 8);
            esum[rf][r] = s;
        }
    if (l15 == 0) {
        #pragma unroll
        for (int rf = 0; rf < 4; rf++)
            #pragma unroll
            for (int r = 0; r < 4; r++)
                eps[w * 64 + rf * 16 + lg * 4 + r] = esum[rf][r];
    }
    __syncthreads();

    // ---- p = exp(e), z ----
    if (tid < 64) {
        float e = eps[tid] + eps[64 + tid] + eps[128 + tid] + eps[192 + tid];
        float p = __expf(e);   // |e| <= ||Wsc||_1 ~ 10.2: no overflow; softmax shift-invariant
        p_out[bt0 + tid] = p;
        pl[tid] = p;
        float z = p;
        z += __shfl_xor(z, 1); z += __shfl_xor(z, 2); z += __shfl_xor(z, 4);
        z += __shfl_xor(z, 8); z += __shfl_xor(z, 16); z += __shfl_xor(z, 32);
        if (tid == 0) zbuf[blockIdx.x] = z;
    }
    __syncthreads();

    // ---- ctx partial from LDS A-tile: thread = (col-pair d2, row-half rh) ----
    {
        int d2 = tid & 127, rh = tid >> 7;
        float a0 = 0.f, a1 = 0.f;
        #pragma unroll 8
        for (int t = 0; t < 32; ++t) {
            int tt = rh * 32 + t;
            unsigned v = *(const unsigned*)&Al[tt * APITCH + d2 * 2];
            float pv = pl[tt];
            a0 += pv * bf2f(v & 0xffffu);
            a1 += pv * bf2f(v >> 16);
        }
        r2[rh * 256 + d2 * 2]     = a0;
        r2[rh * 256 + d2 * 2 + 1] = a1;
    }
    __syncthreads();
    ctxp[((size_t)(c * 256 + b)) * 256 + tid] = r2[tid] + r2[256 + tid];
}

// ---------------- K2: finalize alpha + ctx ----------------
__global__ __launch_bounds__(256) void k_finalize(
    const float* __restrict__ p, const float* __restrict__ zbuf,
    const float* __restrict__ ctxp, float* __restrict__ alpha, float* __restrict__ ctx)
{
    int b = blockIdx.x, t = threadIdx.x;
    float Z = 0.f;
    #pragma unroll
    for (int cc = 0; cc < 8; ++cc) Z += zbuf[b * 8 + cc];
    float inv = 1.f / Z;
    alpha[b * 512 + t] = p[b * 512 + t] * inv;
    alpha[b * 512 + 256 + t] = p[b * 512 + 256 + t] * inv;
    float s = 0.f;
    #pragma unroll
    for (int cc = 0; cc < 8; ++cc) s += ctxp[((size_t)(cc * 256 + b)) * 256 + t];
    ctx[b * 256 + t] = s * inv;
}

// ---------------- K3: gates GEMM (256x1024, K=608=19x32) + LSTM, barrier-free K-loop ----------------
// grid (4,16) x 256 thr. Wave w = rows [rb+w*16, +16); cols = 64 gate-interleaved (n'=h*4+g).
// A and B fragments loaded per-lane directly from global (L2-resident), fp32 -> bf16 via cvt_pk.
__global__ __launch_bounds__(256) void k_gates_lstm(
    const float* __restrict__ ctx, const float* __restrict__ onehot,
    const float* __restrict__ prev_h, const float* __restrict__ W_ih,
    const float* __restrict__ W_hh, const float* __restrict__ b_ih,
    const float* __restrict__ b_hh, const float* __restrict__ prev_c,
    float* __restrict__ out)
{
    __shared__ float Gt[64 * 65];
    const int tid = threadIdx.x;
    const int lane = tid & 63;
    const int w = tid >> 6;
    const int l15 = lane & 15, lg = lane >> 4;
    const int rb = blockIdx.x * 64;
    const int hb = blockIdx.y;

    const int arow = rb + w * 16 + l15;
    // per-cf weight-row bases (lane-varying)
    const float* wih[4]; const float* whh[4];
    #pragma unroll
    for (int cf = 0; cf < 4; cf++) {
        int np = hb * 64 + cf * 16 + l15;
        int hh = np >> 2, gg = np & 3;
        wih[cf] = W_ih + (size_t)(gg * 256 + hh) * 352;
        whh[cf] = W_hh + (size_t)(gg * 256 + hh) * 256;
    }

    f32x4 acc[4];
    #pragma unroll
    for (int j = 0; j < 4; j++) acc[j] = (f32x4){0.f, 0.f, 0.f, 0.f};

    #pragma unroll 4
    for (int kc = 0; kc < 19; ++kc) {
        int k0 = kc * 32 + lg * 8;
        const float* pa;
        if (k0 < 256)      pa = ctx    + (size_t)arow * 256 + k0;
        else if (k0 < 352) pa = onehot + (size_t)arow * 96  + (k0 - 256);
        else               pa = prev_h + (size_t)arow * 256 + (k0 - 352);
        float4 x0 = *(const float4*)pa, x1 = *(const float4*)(pa + 4);
        short8 af; *(int4*)&af = pack8(x0, x1);
        short8 bfr[4];
        #pragma unroll
        for (int cf = 0; cf < 4; cf++) {
            const float* pb = (k0 < 352) ? (wih[cf] + k0) : (whh[cf] + (k0 - 352));
            float4 y0 = *(const float4*)pb, y1 = *(const float4*)(pb + 4);
            *(int4*)&bfr[cf] = pack8(y0, y1);
        }
        #pragma unroll
        for (int cf = 0; cf < 4; cf++)
            acc[cf] = __builtin_amdgcn_mfma_f32_16x16x32_bf16(af, bfr[cf], acc[cf], 0, 0, 0);
    }

    #pragma unroll
    for (int cf = 0; cf < 4; cf++) {
        int col = cf * 16 + l15;
        int np = hb * 64 + col;
        int hg = np >> 2, g = np & 3;
        float bias = b_ih[g * 256 + hg] + b_hh[g * 256 + hg];
        #pragma unroll
        for (int r = 0; r < 4; r++)
            Gt[(w * 16 + lg * 4 + r) * 65 + col] = acc[cf][r] + bias;
    }
    __syncthreads();

    #pragma unroll
    for (int it = 0; it < 4; ++it) {
        int elem = it * 256 + tid;               // < 1024
        int row = elem >> 4, hl = elem & 15;
        float gi = Gt[row * 65 + hl * 4 + 0];
        float gf = Gt[row * 65 + hl * 4 + 1];
        float gg = Gt[row * 65 + hl * 4 + 2];
        float go = Gt[row * 65 + hl * 4 + 3];
        int bg = rb + row, hglob = hb * 16 + hl;
        float cv = sigmoid_fast(gf) * prev_c[bg * 256 + hglob] + sigmoid_fast(gi) * tanh_fast(gg);
        out[bg * 256 + hglob] = sigmoid_fast(go) * tanh_fast(cv);
        out[65536 + bg * 256 + hglob] = cv;
    }
}

extern "C" void kernel_launch(void* const* d_in, const int* in_sizes, int n_in,
                              void* d_out, int out_size, void* d_ws, size_t ws_size,
                              hipStream_t stream) {
    (void)in_sizes; (void)n_in; (void)out_size; (void)ws_size;
    const float* prev_h  = (const float*)d_in[0];
    const float* prev_c  = (const float*)d_in[1];
    const float* batch_H = (const float*)d_in[2];
    const float* onehot  = (const float*)d_in[3];
    const float* W_i2h   = (const float*)d_in[4];
    const float* W_h2h   = (const float*)d_in[5];
    const float* b_h2h   = (const float*)d_in[6];
    const float* W_score = (const float*)d_in[7];
    const float* W_ih    = (const float*)d_in[8];
    const float* W_hh    = (const float*)d_in[9];
    const float* b_ih    = (const float*)d_in[10];
    const float* b_hh    = (const float*)d_in[11];

    char* ws = (char*)d_ws;
    float* hid   = (float*)(ws + WS_HID);
    float* p     = (float*)(ws + WS_P);
    float* zbuf  = (float*)(ws + WS_Z);
    float* ctx   = (float*)(ws + WS_CTX);
    float* ctxp  = (float*)(ws + WS_CTXP);
    short* Wbf   = (short*)(ws + WS_WBF);

    float* out = (float*)d_out;
    float* alpha = out + 131072;            // h:[0,64K) c:[64K,128K) alpha:[128K,256K) floats

    hipLaunchKernelGGL(k_prep,       dim3(288),    dim3(256), 0, stream,
                       prev_h, W_i2h, W_h2h, b_h2h, hid, Wbf);
    hipLaunchKernelGGL(k_escore_ctx, dim3(2048),   dim3(256), 0, stream,
                       batch_H, Wbf, hid, W_score, p, zbuf, ctxp);
    hipLaunchKernelGGL(k_finalize,   dim3(256),    dim3(256), 0, stream,
                       p, zbuf, ctxp, alpha, ctx);
    hipLaunchKernelGGL(k_gates_lstm, dim3(4, 16),  dim3(256), 0, stream,
                       ctx, onehot, prev_h, W_ih, W_hh, b_ih, b_hh, prev_c, out);
}

// Round 7
// 73.619 us; speedup vs baseline: 1.6469x; 1.6469x over previous
//
#include <hip/hip_runtime.h>

typedef __attribute__((ext_vector_type(8))) short short8;
typedef __attribute__((ext_vector_type(4))) float f32x4;

#define KPAD 40     // B chunk row: 32 data + 8 pad shorts (80B stride, 2-way banks)
#define APITCH 264  // A row pitch in shorts: 256 data + 8 pad (528B stride, 2-way banks)

// workspace layout (bytes)
#define WS_HID   0u        // 256*256 f32      = 262144
#define WS_P     262144u   // 131072 f32       = 524288
#define WS_Z     786432u   // 2048 f32         = 8192
#define WS_CTX   794624u   // 256*256 f32      = 262144
#define WS_CTXP  1056768u  // 8*256*256 f32    = 2097152 (ends 3153920)
#define WS_WBF   3153920u  // 8*256*40 bf16    = 163840  (ends 3317760)

__device__ __forceinline__ unsigned cvtpk(float lo, float hi) {
    unsigned r;
    asm("v_cvt_pk_bf16_f32 %0, %1, %2" : "=v"(r) : "v"(lo), "v"(hi));
    return r;
}
__device__ __forceinline__ int4 pack8(float4 x0, float4 x1) {
    int4 q;
    q.x = (int)cvtpk(x0.x, x0.y);
    q.y = (int)cvtpk(x0.z, x0.w);
    q.z = (int)cvtpk(x1.x, x1.y);
    q.w = (int)cvtpk(x1.z, x1.w);
    return q;
}
__device__ __forceinline__ float bf2f(unsigned s) {
    union { float f; unsigned u; } v; v.u = s << 16;
    return v.f;
}
__device__ __forceinline__ float tanh_fast(float x) {
    float e2 = __expf(2.f * x);
    return 1.f - 2.f * __builtin_amdgcn_rcpf(e2 + 1.f);
}
__device__ __forceinline__ float sigmoid_fast(float x) {
    return __builtin_amdgcn_rcpf(1.f + __expf(-x));
}
__device__ __forceinline__ void gload16(const void* g, void* l) {
    __builtin_amdgcn_global_load_lds((const __attribute__((address_space(1))) void*)g,
                                     (__attribute__((address_space(3))) void*)l, 16, 0, 0);
}

// ---------------- K0: hid GEMV + W_i2h bf16 pre-chunking [8][256][40] ----------------
__global__ __launch_bounds__(256) void k_prep(
    const float* __restrict__ prev_h, const float* __restrict__ W_i2h,
    const float* __restrict__ W_h2h, const float* __restrict__ b_h2h,
    float* __restrict__ hid, short* __restrict__ Wbf)
{
    int bid = blockIdx.x, tid = threadIdx.x;
    if (bid < 256) {                       // hid[b][h] = prev_h[b]·W_h2h[h] + b_h2h[h]
        __shared__ float ph[256];
        ph[tid] = prev_h[bid * 256 + tid];
        __syncthreads();
        float acc = b_h2h[tid];
        const float4* w = (const float4*)(W_h2h + tid * 256);
        #pragma unroll 8
        for (int k4 = 0; k4 < 64; ++k4) {
            float4 ww = w[k4];
            acc += ww.x * ph[k4*4+0] + ww.y * ph[k4*4+1] + ww.z * ph[k4*4+2] + ww.w * ph[k4*4+3];
        }
        hid[bid * 256 + tid] = acc;
    } else {                               // W_i2h -> bf16 chunks [8][256][40]
        int idx = (bid - 256) * 256 + tid;         // < 81920
        int kc = idx / (256 * KPAD);
        int rem = idx % (256 * KPAD);
        int n = rem / KPAD, kk = rem % KPAD;
        float v = 0.f;
        if (kk < 32) {
            union { float f; unsigned u; } t; t.f = W_i2h[n * 256 + kc * 32 + kk];
            t.u = (t.u + 0x7FFFu + ((t.u >> 16) & 1u)) & 0xFFFF0000u;  // RNE to bf16
            v = t.f;
        }
        union { float f; unsigned u; } o; o.f = v;
        Wbf[idx] = (short)(o.u >> 16);
    }
}

// ---------------- K1: fused e-score + exp + context partial ----------------
// 2048 blocks x 256 thr (4 waves). Tile 64 bt-rows x 256 h-cols; wave = 64-col panel.
// A staged UP-FRONT (coalesced, 1 barrier) to resident LDS [64][APITCH].
// B: global_load_lds DMA of pre-chunked Wbf, double-buffered, DMA(ks+1) issued before
// compute of ks. Epilogue: p=exp(e) shift-free (|e| <= ||Wsc||_1 ~ 10), ctx from LDS
// with conflict-free row-major lane mapping.
__global__ __launch_bounds__(256, 2) void k_escore_ctx(
    const float* __restrict__ BH, const short* __restrict__ Wbf,
    const float* __restrict__ hid, const float* __restrict__ Wsc,
    float* __restrict__ p_out, float* __restrict__ zbuf, float* __restrict__ ctxp)
{
    __shared__ char smem[74752];
    short* Al = (short*)smem;                   // [64][APITCH] resident A (33792 B)
    char*  BlB = smem + 33792;                  // [2][256][40] B dbuf, DMA dest (40960 B)
    short* Bl = (short*)BlB;
    // epilogue overlays (B dead after K-loop):
    float* eps = (float*)BlB;                   // [4][64]  1024 B
    float* pl  = (float*)(BlB + 1024);          // [64]
    float* r4  = (float*)(BlB + 1280);          // [4][256] 4096 B

    const int tid = threadIdx.x;
    const int lane = tid & 63;
    const int w = tid >> 6;                     // col-panel 0..3
    const int l15 = lane & 15, lg = lane >> 4;
    const int bt0 = blockIdx.x * 64;
    const int b = bt0 >> 9;
    const int c = (bt0 >> 6) & 7;

    // ---- prologue: B chunk 0 DMA + A tile staged up-front ----
    {
        const char* gs0 = (const char*)Wbf + tid * 16;
        #pragma unroll
        for (int s = 0; s < 5; ++s)
            gload16(gs0 + s * 4096, BlB + s * 4096 + tid * 16);
    }
    {
        // A tile = 64KB contiguous; thread reads 8 floats per round, 8 rounds, coalesced
        const float* as = BH + (size_t)bt0 * 256 + tid * 8;
        const int row0 = tid >> 5, colw = (tid & 31) * 8;
        #pragma unroll
        for (int i = 0; i < 8; ++i) {
            float4 x0 = *(const float4*)(as + i * 2048);
            float4 x1 = *(const float4*)(as + i * 2048 + 4);
            *(int4*)&Al[(i * 8 + row0) * APITCH + colw] = pack8(x0, x1);
        }
    }
    __syncthreads();

    // ---- K-loop: B dbuf, DMA issued ahead of compute ----
    f32x4 acc[4][4];
    #pragma unroll
    for (int i = 0; i < 4; i++)
        #pragma unroll
        for (int j = 0; j < 4; j++) acc[i][j] = (f32x4){0.f, 0.f, 0.f, 0.f};

    #pragma unroll
    for (int ks = 0; ks < 8; ++ks) {
        const int cur = ks & 1;
        if (ks < 7) {
            const char* gsb = (const char*)Wbf + (size_t)(ks + 1) * 20480 + tid * 16;
            char* lsb = BlB + (cur ^ 1) * 20480 + tid * 16;
            #pragma unroll
            for (int s = 0; s < 5; ++s)
                gload16(gsb + s * 4096, lsb + s * 4096);
        }
        short8 af[4], bfr[4];
        #pragma unroll
        for (int rf = 0; rf < 4; rf++)
            af[rf] = *(const short8*)&Al[(rf * 16 + l15) * APITCH + ks * 32 + lg * 8];
        #pragma unroll
        for (int cf = 0; cf < 4; cf++)
            bfr[cf] = *(const short8*)&Bl[cur * 10240 + (w * 64 + cf * 16 + l15) * KPAD + lg * 8];
        #pragma unroll
        for (int rf = 0; rf < 4; rf++)
            #pragma unroll
            for (int cf = 0; cf < 4; cf++)
                acc[rf][cf] = __builtin_amdgcn_mfma_f32_16x16x32_bf16(af[rf], bfr[cf], acc[rf][cf], 0, 0, 0);
        __syncthreads();
    }

    // ---- e partials over this wave's 64 cols ----
    float esum[4][4];
    #pragma unroll
    for (int rf = 0; rf < 4; rf++)
        #pragma unroll
        for (int r = 0; r < 4; r++) esum[rf][r] = 0.f;

    #pragma unroll
    for (int cf = 0; cf < 4; cf++) {
        int col = w * 64 + cf * 16 + l15;
        float wsv = Wsc[col];
        float hd = hid[b * 256 + col];
        #pragma unroll
        for (int rf = 0; rf < 4; rf++)
            #pragma unroll
            for (int r = 0; r < 4; r++)
                esum[rf][r] += wsv * tanh_fast(acc[rf][cf][r] + hd);
    }
    #pragma unroll
    for (int rf = 0; rf < 4; rf++)
        #pragma unroll
        for (int r = 0; r < 4; r++) {
            float s = esum[rf][r];
            s += __shfl_xor(s, 1); s += __shfl_xor(s, 2);
            s += __shfl_xor(s, 4); s += __shfl_xor(s, 8);
            esum[rf][r] = s;
        }
    if (l15 == 0) {
        #pragma unroll
        for (int rf = 0; rf < 4; rf++)
            #pragma unroll
            for (int r = 0; r < 4; r++)
                eps[w * 64 + rf * 16 + lg * 4 + r] = esum[rf][r];
    }
    __syncthreads();

    // ---- p = exp(e), z ----
    if (tid < 64) {
        float e = eps[tid] + eps[64 + tid] + eps[128 + tid] + eps[192 + tid];
        float p = __expf(e);   // |e| <= ||Wsc||_1 ~ 10.2: no overflow; softmax shift-invariant
        p_out[bt0 + tid] = p;
        pl[tid] = p;
        float z = p;
        z += __shfl_xor(z, 1); z += __shfl_xor(z, 2); z += __shfl_xor(z, 4);
        z += __shfl_xor(z, 8); z += __shfl_xor(z, 16); z += __shfl_xor(z, 32);
        if (tid == 0) zbuf[blockIdx.x] = z;
    }
    __syncthreads();

    // ---- ctx partial: wave w owns rows 16w..16w+15; lanes span d (conflict-free) ----
    {
        float c0 = 0.f, c1 = 0.f, c2 = 0.f, c3 = 0.f;
        #pragma unroll
        for (int t = 0; t < 16; ++t) {
            int row = w * 16 + t;
            float pv = pl[row];                                   // LDS broadcast
            unsigned v1 = *(const unsigned*)&Al[row * APITCH + lane * 2];
            unsigned v2 = *(const unsigned*)&Al[row * APITCH + 128 + lane * 2];
            c0 += pv * bf2f(v1 & 0xffffu); c1 += pv * bf2f(v1 >> 16);
            c2 += pv * bf2f(v2 & 0xffffu); c3 += pv * bf2f(v2 >> 16);
        }
        r4[w * 256 + lane * 2]       = c0;
        r4[w * 256 + lane * 2 + 1]   = c1;
        r4[w * 256 + 128 + lane * 2] = c2;
        r4[w * 256 + 129 + lane * 2] = c3;
    }
    __syncthreads();
    ctxp[((size_t)(c * 256 + b)) * 256 + tid] = r4[tid] + r4[256 + tid] + r4[512 + tid] + r4[768 + tid];
}

// ---------------- K2: finalize alpha + ctx ----------------
__global__ __launch_bounds__(256) void k_finalize(
    const float* __restrict__ p, const float* __restrict__ zbuf,
    const float* __restrict__ ctxp, float* __restrict__ alpha, float* __restrict__ ctx)
{
    int b = blockIdx.x, t = threadIdx.x;
    float Z = 0.f;
    #pragma unroll
    for (int cc = 0; cc < 8; ++cc) Z += zbuf[b * 8 + cc];
    float inv = 1.f / Z;
    alpha[b * 512 + t] = p[b * 512 + t] * inv;
    alpha[b * 512 + 256 + t] = p[b * 512 + 256 + t] * inv;
    float s = 0.f;
    #pragma unroll
    for (int cc = 0; cc < 8; ++cc) s += ctxp[((size_t)(cc * 256 + b)) * 256 + t];
    ctx[b * 256 + t] = s * inv;
}

// ---------------- K3: gates GEMM (256x1024, K=608=19x32) fused with LSTM ----------------
// grid (4,16); block tile 64 rows x 64 gate-interleaved cols (n' = h*4+g).
// A assembled from [ctx|onehot|prev_h]; B staged fp32->bf16 from W_ih/W_hh in-block.
__global__ __launch_bounds__(256) void k_gates_lstm(
    const float* __restrict__ ctx, const float* __restrict__ onehot,
    const float* __restrict__ prev_h, const float* __restrict__ W_ih,
    const float* __restrict__ W_hh, const float* __restrict__ b_ih,
    const float* __restrict__ b_hh, const float* __restrict__ prev_c,
    float* __restrict__ out)
{
    __shared__ char smem[20800];
    short* AlB = (short*)smem;            // [2][64*KPAD]
    short* BlB = (short*)smem + 5120;     // [2][64*KPAD]
    const int tid = threadIdx.x;
    const int lane = tid & 63;
    const int w = tid >> 6;
    const int l15 = lane & 15, lg = lane >> 4;
    const int rb = blockIdx.x * 64;
    const int hb = blockIdx.y;

    f32x4 acc[4];
    #pragma unroll
    for (int j = 0; j < 4; j++) acc[j] = (f32x4){0.f, 0.f, 0.f, 0.f};

    const int arow = tid >> 2, akg = tid & 3;
    const int rg = rb + arow;
    const int bn = tid >> 2, bq = tid & 3;
    const int np_ = hb * 64 + bn, hh_ = np_ >> 2, gg_ = np_ & 3;
    const float* wih_row = W_ih + (size_t)(gg_ * 256 + hh_) * 352;
    const float* whh_row = W_hh + (size_t)(gg_ * 256 + hh_) * 256;

    auto stageAB = [&](int kc, int bu) {
        int k0 = kc * 32 + akg * 8;
        const float4* pa;
        if (k0 < 256)      pa = (const float4*)(ctx    + rg * 256 + k0);
        else if (k0 < 352) pa = (const float4*)(onehot + rg * 96  + (k0 - 256));
        else               pa = (const float4*)(prev_h + rg * 256 + (k0 - 352));
        float4 x0 = pa[0], x1 = pa[1];
        *(int4*)&AlB[bu * 2560 + arow * KPAD + akg * 8] = pack8(x0, x1);
        int kb = kc * 32 + bq * 8;
        const float* pb = (kb < 352) ? (wih_row + kb) : (whh_row + (kb - 352));
        float4 y0 = *(const float4*)pb, y1 = *(const float4*)(pb + 4);
        *(int4*)&BlB[bu * 2560 + bn * KPAD + bq * 8] = pack8(y0, y1);
    };

    stageAB(0, 0);
    __syncthreads();

    for (int kc = 0; kc < 19; ++kc) {
        int cur = kc & 1;
        short8 af = *(const short8*)&AlB[cur * 2560 + (w * 16 + l15) * KPAD + lg * 8];
        short8 bfr[4];
        #pragma unroll
        for (int cf = 0; cf < 4; cf++)
            bfr[cf] = *(const short8*)&BlB[cur * 2560 + (cf * 16 + l15) * KPAD + lg * 8];
        if (kc < 18) stageAB(kc + 1, cur ^ 1);
        #pragma unroll
        for (int cf = 0; cf < 4; cf++)
            acc[cf] = __builtin_amdgcn_mfma_f32_16x16x32_bf16(af, bfr[cf], acc[cf], 0, 0, 0);
        __syncthreads();
    }

    float* Gt = (float*)smem;                    // [64][65]
    #pragma unroll
    for (int cf = 0; cf < 4; cf++) {
        int col = cf * 16 + l15;
        int np = hb * 64 + col;
        int hg = np >> 2, g = np & 3;
        float bias = b_ih[g * 256 + hg] + b_hh[g * 256 + hg];
        #pragma unroll
        for (int r = 0; r < 4; r++)
            Gt[(w * 16 + lg * 4 + r) * 65 + col] = acc[cf][r] + bias;
    }
    __syncthreads();

    #pragma unroll
    for (int it = 0; it < 4; ++it) {
        int elem = it * 256 + tid;               // < 1024
        int row = elem >> 4, hl = elem & 15;
        float gi = Gt[row * 65 + hl * 4 + 0];
        float gf = Gt[row * 65 + hl * 4 + 1];
        float gg = Gt[row * 65 + hl * 4 + 2];
        float go = Gt[row * 65 + hl * 4 + 3];
        int bg = rb + row, hglob = hb * 16 + hl;
        float cv = sigmoid_fast(gf) * prev_c[bg * 256 + hglob] + sigmoid_fast(gi) * tanh_fast(gg);
        out[bg * 256 + hglob] = sigmoid_fast(go) * tanh_fast(cv);
        out[65536 + bg * 256 + hglob] = cv;
    }
}

extern "C" void kernel_launch(void* const* d_in, const int* in_sizes, int n_in,
                              void* d_out, int out_size, void* d_ws, size_t ws_size,
                              hipStream_t stream) {
    (void)in_sizes; (void)n_in; (void)out_size; (void)ws_size;
    const float* prev_h  = (const float*)d_in[0];
    const float* prev_c  = (const float*)d_in[1];
    const float* batch_H = (const float*)d_in[2];
    const float* onehot  = (const float*)d_in[3];
    const float* W_i2h   = (const float*)d_in[4];
    const float* W_h2h   = (const float*)d_in[5];
    const float* b_h2h   = (const float*)d_in[6];
    const float* W_score = (const float*)d_in[7];
    const float* W_ih    = (const float*)d_in[8];
    const float* W_hh    = (const float*)d_in[9];
    const float* b_ih    = (const float*)d_in[10];
    const float* b_hh    = (const float*)d_in[11];

    char* ws = (char*)d_ws;
    float* hid   = (float*)(ws + WS_HID);
    float* p     = (float*)(ws + WS_P);
    float* zbuf  = (float*)(ws + WS_Z);
    float* ctx   = (float*)(ws + WS_CTX);
    float* ctxp  = (float*)(ws + WS_CTXP);
    short* Wbf   = (short*)(ws + WS_WBF);

    float* out = (float*)d_out;
    float* alpha = out + 131072;            // h:[0,64K) c:[64K,128K) alpha:[128K,256K) floats

    hipLaunchKernelGGL(k_prep,       dim3(576),    dim3(256), 0, stream,
                       prev_h, W_i2h, W_h2h, b_h2h, hid, Wbf);
    hipLaunchKernelGGL(k_escore_ctx, dim3(2048),   dim3(256), 0, stream,
                       batch_H, Wbf, hid, W_score, p, zbuf, ctxp);
    hipLaunchKernelGGL(k_finalize,   dim3(256),    dim3(256), 0, stream,
                       p, zbuf, ctxp, alpha, ctx);
    hipLaunchKernelGGL(k_gates_lstm, dim3(4, 16),  dim3(256), 0, stream,
                       ctx, onehot, prev_h, W_ih, W_hh, b_ih, b_hh, prev_c, out);
}